// Round 5
// baseline (367.087 us; speedup 1.0000x reference)
//
#include <hip/hip_runtime.h>
#include <math.h>

// Problem constants (fixed by reference): B=4, C=64, pooled 32^3, out 64^3.
#define NBC   256      // B*C
#define SP    32768    // 32^3 pooled elements per (b,c)
#define SO    262144   // 64^3 output elements per (b,c)
#define PARTS 8        // partial-sum blocks per channel

// native vector types: __builtin_nontemporal_* rejects HIP_vector_type
typedef float vfloat4 __attribute__((ext_vector_type(4)));
typedef int   vint4   __attribute__((ext_vector_type(4)));

// Pass 1: partial silu-sums per (b,c). 2048 blocks (= 256 channels x 8 parts),
// 256 threads, 4 independent float4 loads per thread -> latency-hidden.
// No atomics / no zero-init: every partial slot is written exactly once.
__global__ __launch_bounds__(256) void gate_partial_kernel(
    const float* __restrict__ pooled, float* __restrict__ partial)
{
    const int blk  = blockIdx.x;          // bc*PARTS + part
    const int bc   = blk >> 3;
    const int part = blk & 7;
    const int t    = threadIdx.x;

    const float4* p4 = (const float4*)(pooled + (size_t)bc * SP) + part * 1024;

    float4 v0 = p4[0 * 256 + t];
    float4 v1 = p4[1 * 256 + t];
    float4 v2 = p4[2 * 256 + t];
    float4 v3 = p4[3 * 256 + t];

    float s = 0.f;
    s += v0.x / (1.f + __expf(-v0.x)) + v0.y / (1.f + __expf(-v0.y))
       + v0.z / (1.f + __expf(-v0.z)) + v0.w / (1.f + __expf(-v0.w));
    s += v1.x / (1.f + __expf(-v1.x)) + v1.y / (1.f + __expf(-v1.y))
       + v1.z / (1.f + __expf(-v1.z)) + v1.w / (1.f + __expf(-v1.w));
    s += v2.x / (1.f + __expf(-v2.x)) + v2.y / (1.f + __expf(-v2.y))
       + v2.z / (1.f + __expf(-v2.z)) + v2.w / (1.f + __expf(-v2.w));
    s += v3.x / (1.f + __expf(-v3.x)) + v3.y / (1.f + __expf(-v3.y))
       + v3.z / (1.f + __expf(-v3.z)) + v3.w / (1.f + __expf(-v3.w));

    // wave64 reduce
    #pragma unroll
    for (int off = 32; off > 0; off >>= 1)
        s += __shfl_down(s, off, 64);

    __shared__ float ls[4];
    if ((t & 63) == 0) ls[t >> 6] = s;
    __syncthreads();
    if (t == 0) partial[blk] = ls[0] + ls[1] + ls[2] + ls[3];
}

// Pass 2: gather-style unpool+gate, coarsened: each thread owns 4 adjacent
// pooled windows along w' (flat window index 4q..4q+3) and writes the
// corresponding 2x2x2 output blocks: 8 float4 stores covering two full
// 8-float w-segments on each of 4 output rows. Per store instruction each
// 8-lane group writes a dense 128 B line -> no RMW fetch. Input reads and
// output writes are both pure streams -> nontemporal.
__global__ __launch_bounds__(256) void unpool_kernel(
    const float* __restrict__ pooled, const int* __restrict__ idx,
    const float* __restrict__ partial, float* __restrict__ out)
{
    const int bc = blockIdx.x >> 5;                        // 32 blocks per (b,c)
    const int q  = ((blockIdx.x & 31) << 8) | threadIdx.x; // quad index [0,8192)

    // finish the channel reduction (block-uniform -> scalar loads)
    const float* pp = partial + bc * PARTS;
    float tot = 0.f;
    #pragma unroll
    for (int i = 0; i < PARTS; ++i) tot += pp[i];
    const float m = tot * (1.f / (float)SO);
    const float g = (m >= 0.f) ? -log1pf(__expf(-m)) : m - log1pf(__expf(m));

    const size_t sbase = (size_t)bc * SP + 4 * (size_t)q;
    const vfloat4 v  = __builtin_nontemporal_load((const vfloat4*)(pooled + sbase));
    const vint4   ix = __builtin_nontemporal_load((const vint4*)(idx + sbase));

    const float gv0 = g * v.x, gv1 = g * v.y, gv2 = g * v.z, gv3 = g * v.w;

    // 3-bit slot code per window: od*4 + oh*2 + ow  (parity bits of d,h,w)
    const int c0 = (((ix.x >> 12) & 1) << 2) | (((ix.x >> 6) & 1) << 1) | (ix.x & 1);
    const int c1 = (((ix.y >> 12) & 1) << 2) | (((ix.y >> 6) & 1) << 1) | (ix.y & 1);
    const int c2 = (((ix.z >> 12) & 1) << 2) | (((ix.z >> 6) & 1) << 1) | (ix.z & 1);
    const int c3 = (((ix.w >> 12) & 1) << 2) | (((ix.w >> 6) & 1) << 1) | (ix.w & 1);

    // q = d'*256 + h'*8 + qw  (qw in [0,8), covers w'=4qw..4qw+3)
    const int dp = q >> 8;
    const int hp = (q >> 3) & 31;
    const int qw = q & 7;

    float* ob = out + (size_t)bc * SO
                    + (size_t)(dp * 2) * 4096   // d stride = 64*64
                    + (hp * 2) * 64             // h stride = 64
                    + qw * 8;                   // w = 8*qw .. 8*qw+7

    #pragma unroll
    for (int rr = 0; rr < 2; ++rr) {
        #pragma unroll
        for (int cc = 0; cc < 2; ++cc) {
            const int s0 = (rr << 2) | (cc << 1);
            vfloat4 f0, f1;
            f0.x = (c0 == s0)       ? gv0 : 0.f;
            f0.y = (c0 == (s0 | 1)) ? gv0 : 0.f;
            f0.z = (c1 == s0)       ? gv1 : 0.f;
            f0.w = (c1 == (s0 | 1)) ? gv1 : 0.f;
            f1.x = (c2 == s0)       ? gv2 : 0.f;
            f1.y = (c2 == (s0 | 1)) ? gv2 : 0.f;
            f1.z = (c3 == s0)       ? gv3 : 0.f;
            f1.w = (c3 == (s0 | 1)) ? gv3 : 0.f;
            float* row = ob + rr * 4096 + cc * 64;
            __builtin_nontemporal_store(f0, (vfloat4*)row);
            __builtin_nontemporal_store(f1, (vfloat4*)(row + 4));
        }
    }
}

extern "C" void kernel_launch(void* const* d_in, const int* in_sizes, int n_in,
                              void* d_out, int out_size, void* d_ws, size_t ws_size,
                              hipStream_t stream) {
    const float* pooled  = (const float*)d_in[0];
    const int*   indices = (const int*)d_in[1];
    float*       out     = (float*)d_out;
    float*       partial = (float*)d_ws;   // NBC*PARTS floats of scratch

    gate_partial_kernel<<<NBC * PARTS, 256, 0, stream>>>(pooled, partial);
    unpool_kernel<<<NBC * 32, 256, 0, stream>>>(pooled, indices, partial, out);
}

// Round 6
// 318.915 us; speedup vs baseline: 1.1511x; 1.1511x over previous
//
#include <hip/hip_runtime.h>
#include <math.h>

// Problem constants (fixed by reference): B=4, C=64, pooled 32^3, out 64^3.
#define NBC   256      // B*C
#define SP    32768    // 32^3 pooled elements per (b,c)
#define SO    262144   // 64^3 output elements per (b,c)
#define PARTS 8        // partial-sum blocks per channel

// Pass 1: partial silu-sums per (b,c). 2048 blocks (= 256 channels x 8 parts),
// 256 threads, 4 independent float4 loads per thread -> latency-hidden.
// No atomics / no zero-init: every partial slot is written exactly once.
__global__ __launch_bounds__(256) void gate_partial_kernel(
    const float* __restrict__ pooled, float* __restrict__ partial)
{
    const int blk  = blockIdx.x;          // bc*PARTS + part
    const int bc   = blk >> 3;
    const int part = blk & 7;
    const int t    = threadIdx.x;

    const float4* p4 = (const float4*)(pooled + (size_t)bc * SP) + part * 1024;

    float4 v0 = p4[0 * 256 + t];
    float4 v1 = p4[1 * 256 + t];
    float4 v2 = p4[2 * 256 + t];
    float4 v3 = p4[3 * 256 + t];

    float s = 0.f;
    s += v0.x / (1.f + __expf(-v0.x)) + v0.y / (1.f + __expf(-v0.y))
       + v0.z / (1.f + __expf(-v0.z)) + v0.w / (1.f + __expf(-v0.w));
    s += v1.x / (1.f + __expf(-v1.x)) + v1.y / (1.f + __expf(-v1.y))
       + v1.z / (1.f + __expf(-v1.z)) + v1.w / (1.f + __expf(-v1.w));
    s += v2.x / (1.f + __expf(-v2.x)) + v2.y / (1.f + __expf(-v2.y))
       + v2.z / (1.f + __expf(-v2.z)) + v2.w / (1.f + __expf(-v2.w));
    s += v3.x / (1.f + __expf(-v3.x)) + v3.y / (1.f + __expf(-v3.y))
       + v3.z / (1.f + __expf(-v3.z)) + v3.w / (1.f + __expf(-v3.w));

    // wave64 reduce
    #pragma unroll
    for (int off = 32; off > 0; off >>= 1)
        s += __shfl_down(s, off, 64);

    __shared__ float ls[4];
    if ((t & 63) == 0) ls[t >> 6] = s;
    __syncthreads();
    if (t == 0) partial[blk] = ls[0] + ls[1] + ls[2] + ls[3];
}

// Pass 2: gather-style unpool+gate, h-coarsened but store-dense.
// Each thread owns 2 adjacent windows along w' at h'=hh AND 2 more at
// h'=hh+16 (same d'). All 8 float4 stores keep the R2-proven geometry:
// lanes wp=0..15 of a store instruction cover one full 64-float output
// row segment (dense 256 B) -> every 128 B line fully written, no RMW.
// (R5 lesson: half-dense store instructions + NT = partial-line HBM
// writes, -48 us. Density per instruction is the invariant to protect.)
__global__ __launch_bounds__(256) void unpool_kernel(
    const float* __restrict__ pooled, const int* __restrict__ idx,
    const float* __restrict__ partial, float* __restrict__ out)
{
    const int bc = blockIdx.x >> 5;       // 32 blocks per (b,c)
    const int dp = blockIdx.x & 31;       // d' in [0,32)
    const int t  = threadIdx.x;
    const int hh = t >> 4;                // h' low half: [0,16)
    const int wp = t & 15;                // w-pair: covers w'=2wp, 2wp+1

    // finish the channel reduction (block-uniform -> scalar loads)
    const float* pp = partial + bc * PARTS;
    float tot = 0.f;
    #pragma unroll
    for (int i = 0; i < PARTS; ++i) tot += pp[i];
    const float m = tot * (1.f / (float)SO);
    const float g = (m >= 0.f) ? -log1pf(__expf(-m)) : m - log1pf(__expf(m));

    // pooled window linear index: d'*1024 + h'*32 + w'
    const size_t sbase = (size_t)bc * SP + dp * 1024 + hh * 32 + 2 * wp;
    const float2 va = *(const float2*)(pooled + sbase);         // h' = hh
    const int2   ia = *(const int2*)(idx + sbase);
    const float2 vb = *(const float2*)(pooled + sbase + 512);   // h' = hh+16
    const int2   ib = *(const int2*)(idx + sbase + 512);

    const float ga0 = g * va.x, ga1 = g * va.y;
    const float gb0 = g * vb.x, gb1 = g * vb.y;

    // 3-bit slot code per window: od*4 + oh*2 + ow (parity bits of d,h,w)
    const int cA0 = (((ia.x >> 12) & 1) << 2) | (((ia.x >> 6) & 1) << 1) | (ia.x & 1);
    const int cA1 = (((ia.y >> 12) & 1) << 2) | (((ia.y >> 6) & 1) << 1) | (ia.y & 1);
    const int cB0 = (((ib.x >> 12) & 1) << 2) | (((ib.x >> 6) & 1) << 1) | (ib.x & 1);
    const int cB1 = (((ib.y >> 12) & 1) << 2) | (((ib.y >> 6) & 1) << 1) | (ib.y & 1);

    // output base: d = 2dp, h = 2hh, w = 4wp
    float* ob = out + (size_t)bc * SO
                    + (size_t)(dp * 2) * 4096   // d stride = 64*64
                    + (hh * 2) * 64             // h stride = 64
                    + wp * 4;

    #pragma unroll
    for (int rr = 0; rr < 2; ++rr) {            // d parity
        #pragma unroll
        for (int cc = 0; cc < 2; ++cc) {        // h parity
            const int s0 = (rr << 2) | (cc << 1);
            float4 fa, fb;
            fa.x = (cA0 == s0)       ? ga0 : 0.f;
            fa.y = (cA0 == (s0 | 1)) ? ga0 : 0.f;
            fa.z = (cA1 == s0)       ? ga1 : 0.f;
            fa.w = (cA1 == (s0 | 1)) ? ga1 : 0.f;
            fb.x = (cB0 == s0)       ? gb0 : 0.f;
            fb.y = (cB0 == (s0 | 1)) ? gb0 : 0.f;
            fb.z = (cB1 == s0)       ? gb1 : 0.f;
            fb.w = (cB1 == (s0 | 1)) ? gb1 : 0.f;
            float* row = ob + rr * 4096 + cc * 64;
            *(float4*)row = fa;                  // h rows 2hh, 2hh+1
            *(float4*)(row + 2048) = fb;         // h rows 2hh+32, 2hh+33
        }
    }
}

extern "C" void kernel_launch(void* const* d_in, const int* in_sizes, int n_in,
                              void* d_out, int out_size, void* d_ws, size_t ws_size,
                              hipStream_t stream) {
    const float* pooled  = (const float*)d_in[0];
    const int*   indices = (const int*)d_in[1];
    float*       out     = (float*)d_out;
    float*       partial = (float*)d_ws;   // NBC*PARTS floats of scratch

    gate_partial_kernel<<<NBC * PARTS, 256, 0, stream>>>(pooled, partial);
    unpool_kernel<<<NBC * 32, 256, 0, stream>>>(pooled, indices, partial, out);
}